// Round 1
// baseline (550.433 us; speedup 1.0000x reference)
//
#include <hip/hip_runtime.h>
#include <hip/hip_fp16.h>
#include <stdint.h>

#define NCH 128

using half8  = __attribute__((ext_vector_type(8))) _Float16;
using floatx4 = __attribute__((ext_vector_type(4))) float;

// ---------------- CSR construction ----------------

__global__ __launch_bounds__(256) void count_kernel(const int* __restrict__ dst,
                                                    int* __restrict__ counts, int E) {
    int i = blockIdx.x * blockDim.x + threadIdx.x;
    if (i < E) atomicAdd(&counts[dst[i]], 1);
}

__global__ __launch_bounds__(1024) void scan1_kernel(const int* __restrict__ counts,
                                                     int* __restrict__ incl,
                                                     int* __restrict__ bsums, int n) {
    __shared__ int tmp[1024];
    int i = blockIdx.x * 1024 + threadIdx.x;
    int v = (i < n) ? counts[i] : 0;
    tmp[threadIdx.x] = v;
    __syncthreads();
    for (int off = 1; off < 1024; off <<= 1) {
        int t = (threadIdx.x >= off) ? tmp[threadIdx.x - off] : 0;
        __syncthreads();
        tmp[threadIdx.x] += t;
        __syncthreads();
    }
    if (i < n) incl[i] = tmp[threadIdx.x];
    if (threadIdx.x == 1023) bsums[blockIdx.x] = tmp[1023];
}

__global__ __launch_bounds__(128) void scan2_kernel(int* __restrict__ bsums, int nb) {
    __shared__ int tmp[128];
    int v = (threadIdx.x < nb) ? bsums[threadIdx.x] : 0;
    tmp[threadIdx.x] = v;
    __syncthreads();
    for (int off = 1; off < 128; off <<= 1) {
        int t = (threadIdx.x >= off) ? tmp[threadIdx.x - off] : 0;
        __syncthreads();
        tmp[threadIdx.x] += t;
        __syncthreads();
    }
    if (threadIdx.x < nb) bsums[threadIdx.x] = tmp[threadIdx.x] - v;  // exclusive
}

__global__ __launch_bounds__(256) void offsets_kernel(const int* __restrict__ incl,
                                                      const int* __restrict__ counts,
                                                      const int* __restrict__ bsums,
                                                      int* __restrict__ offsets,
                                                      int* __restrict__ cursor, int n) {
    int i = blockIdx.x * blockDim.x + threadIdx.x;
    if (i < n) {
        int e = incl[i] - counts[i] + bsums[i >> 10];
        offsets[i] = e;
        cursor[i] = e;
    }
}

// fill: 4-byte packed meta (src | (deg+1)<<17). src < 2^17, deg+1 < 2^15.
//
// XCD-range-partitioned scatter: dst space split into 8 contiguous ranges;
// range = blockIdx.x & 7 so all blocks writing one emeta window (~0.8 MB)
// land on the same XCD (round-robin dispatch heuristic). Partial 64B lines
// then accumulate in that XCD's write-back L2 and are evicted once ->
// write traffic ~= payload (6.4 MB) instead of 16x amplified (107 MB).
// Cost: each range-group re-scans the full edge list (L3-resident after
// first touch). Correctness does not depend on the XCD mapping.
__global__ __launch_bounds__(256) void fill_kernel(const int* __restrict__ src,
                                                   const int* __restrict__ dst,
                                                   const int* __restrict__ counts,
                                                   int* __restrict__ cursor,
                                                   unsigned int* __restrict__ emeta,
                                                   int E, int n) {
    int g = blockIdx.x & 7;            // dst-range / XCD group
    int bInG = blockIdx.x >> 3;        // block index within group
    int lo = (int)(((long long)n * g) >> 3);
    int hi = (int)(((long long)n * (g + 1)) >> 3);
    int stride = (gridDim.x >> 3) * blockDim.x;
    for (int i = bInG * blockDim.x + threadIdx.x; i < E; i += stride) {
        int d = dst[i];
        int s = src[i];                // unconditional: coalesced, L3-served
        if (d >= lo && d < hi) {
            unsigned int degp1 = (unsigned int)counts[s] + 1u;
            int pos = atomicAdd(&cursor[d], 1);
            emeta[pos] = (unsigned int)s | (degp1 << 17);
        }
    }
}

// ---------------- W pre-swizzle: W[128][128] fp32 -> B-fragment-order fp16 ----
// Fragment cell c (0..2047): pair p=c>>6 (kc=p>>3, ct=p&7), lane=c&63.
// Cell holds 8 fp16: B[k][n] with n=ct*16+(lane&15), k=kc*32+(lane>>4)*8+j.

__global__ __launch_bounds__(256) void wprep_kernel(const float* __restrict__ W1,
                                                    const float* __restrict__ W2,
                                                    __half* __restrict__ Wt1,
                                                    __half* __restrict__ Wt2) {
    int b = blockIdx.x;                       // 0..15
    const float* W = (b < 8) ? W1 : W2;
    __half* Wt     = (b < 8) ? Wt1 : Wt2;
    int c = (b & 7) * 256 + threadIdx.x;      // 0..2047
    int p = c >> 6, lane = c & 63;
    int kc = p >> 3, ct = p & 7;
    int nn = ct * 16 + (lane & 15);
    int kbase = kc * 32 + (lane >> 4) * 8;
    half8 hv;
#pragma unroll
    for (int j = 0; j < 8; ++j)
        hv[j] = (_Float16)W[(size_t)(kbase + j) * NCH + nn];
    *(half8*)(Wt + (size_t)c * 8) = hv;
}

// ---------------- MFMA GEMM: C[n,128](fp16) = A[n,128](fp32) @ W ----------------
// 256 threads = 4 waves; wave computes 32 rows x 128 cols via 16x16x32 f16 MFMA.
// Wt (fragment-order fp16, 32KB) staged to LDS; epilogue reuses LDS for
// coalesced fp16 row stores.
// Layouts (m89/m120-verified): A[m=lane&15][k=(lane>>4)*8+j],
// B[k=(lane>>4)*8+j][n=lane&15], D col=lane&15 row=(lane>>4)*4+reg.

__global__ __launch_bounds__(256) void gemm_kernel(const float* __restrict__ A,
                                                   const __half* __restrict__ Wt,
                                                   __half* __restrict__ C, int n) {
    __shared__ float4 lds[2048];   // 32 KB
    int t = threadIdx.x;
    for (int i = t; i < 2048; i += 256) lds[i] = ((const float4*)Wt)[i];
    __syncthreads();

    int wave = t >> 6, lane = t & 63;
    int q = lane >> 4, m16 = lane & 15;
    int rowbase = blockIdx.x * 128 + wave * 32;

    floatx4 acc[2][8];
#pragma unroll
    for (int g = 0; g < 2; ++g)
#pragma unroll
        for (int ct = 0; ct < 8; ++ct) {
            acc[g][ct][0] = 0.f; acc[g][ct][1] = 0.f;
            acc[g][ct][2] = 0.f; acc[g][ct][3] = 0.f;
        }

    const half8* bfr = (const half8*)lds;

    int ra0 = min(rowbase + m16, n - 1);
    int ra1 = min(rowbase + 16 + m16, n - 1);
    const float* pa0 = A + (size_t)ra0 * NCH;
    const float* pa1 = A + (size_t)ra1 * NCH;

#pragma unroll
    for (int kc = 0; kc < 4; ++kc) {
        int ko = kc * 32 + q * 8;
        float4 f0 = *(const float4*)(pa0 + ko);
        float4 f1 = *(const float4*)(pa0 + ko + 4);
        float4 g0 = *(const float4*)(pa1 + ko);
        float4 g1 = *(const float4*)(pa1 + ko + 4);
        half8 a0, a1;
        a0[0] = (_Float16)f0.x; a0[1] = (_Float16)f0.y;
        a0[2] = (_Float16)f0.z; a0[3] = (_Float16)f0.w;
        a0[4] = (_Float16)f1.x; a0[5] = (_Float16)f1.y;
        a0[6] = (_Float16)f1.z; a0[7] = (_Float16)f1.w;
        a1[0] = (_Float16)g0.x; a1[1] = (_Float16)g0.y;
        a1[2] = (_Float16)g0.z; a1[3] = (_Float16)g0.w;
        a1[4] = (_Float16)g1.x; a1[5] = (_Float16)g1.y;
        a1[6] = (_Float16)g1.z; a1[7] = (_Float16)g1.w;
#pragma unroll
        for (int ct = 0; ct < 8; ++ct) {
            half8 b = bfr[(kc * 8 + ct) * 64 + lane];
            acc[0][ct] = __builtin_amdgcn_mfma_f32_16x16x32_f16(a0, b, acc[0][ct], 0, 0, 0);
            acc[1][ct] = __builtin_amdgcn_mfma_f32_16x16x32_f16(a1, b, acc[1][ct], 0, 0, 0);
        }
    }

    __syncthreads();   // all waves done with Wt fragments; reuse LDS as scratch
    float* scr = (float*)lds + wave * 2048;   // 16 rows x 128 f32 per wave
#pragma unroll
    for (int g = 0; g < 2; ++g) {
#pragma unroll
        for (int reg = 0; reg < 4; ++reg)
#pragma unroll
            for (int ct = 0; ct < 8; ++ct)
                scr[(q * 4 + reg) * NCH + ct * 16 + m16] = acc[g][ct][reg];
        // within-wave LDS RAW: compiler inserts lgkmcnt wait; no barrier needed
        int row0 = rowbase + g * 16;
#pragma unroll
        for (int r = 0; r < 16; ++r) {
            int row = row0 + r;
            if (row < n) {
                float2 v = *(float2*)(scr + r * NCH + lane * 2);
                __half2 hh = __floats2half2_rn(v.x, v.y);
                *(unsigned int*)(C + (size_t)row * NCH + lane * 2) = *(unsigned int*)&hh;
            }
        }
    }
}

// ---------------- Aggregation ----------------
// One wave per node; h fp16 (256B rows). 4B metas preloaded (coalesced) and
// broadcast via shfl; 4 independent row gathers in flight.

__global__ __launch_bounds__(256) void agg_kernel(const __half2* __restrict__ hp,
                                                  const int* __restrict__ offsets,
                                                  const int* __restrict__ counts,
                                                  const unsigned int* __restrict__ emeta,
                                                  const float* __restrict__ bias,
                                                  float* __restrict__ out,
                                                  int n, int do_relu) {
    int gw = (blockIdx.x * blockDim.x + threadIdx.x) >> 6;
    int lane = threadIdx.x & 63;
    if (gw >= n) return;
    int node = gw;

    int o = offsets[node];
    int c = counts[node];
    float dn = rsqrtf((float)(c + 1));

    float2 hv = __half22float2(hp[(size_t)node * 64 + lane]);
    float w0s = dn * dn;
    float ax = hv.x * w0s, ay = hv.y * w0s;

    unsigned int m = (lane < c) ? emeta[o + lane] : 0u;
    int cc = min(c, 64);
    int j = 0;
    for (; j + 4 <= cc; j += 4) {
        unsigned int p0 = (unsigned int)__shfl((int)m, j);
        unsigned int p1 = (unsigned int)__shfl((int)m, j + 1);
        unsigned int p2 = (unsigned int)__shfl((int)m, j + 2);
        unsigned int p3 = (unsigned int)__shfl((int)m, j + 3);
        int s0 = p0 & 0x1FFFF; float w0 = rsqrtf((float)(p0 >> 17)) * dn;
        int s1 = p1 & 0x1FFFF; float w1 = rsqrtf((float)(p1 >> 17)) * dn;
        int s2 = p2 & 0x1FFFF; float w2 = rsqrtf((float)(p2 >> 17)) * dn;
        int s3 = p3 & 0x1FFFF; float w3 = rsqrtf((float)(p3 >> 17)) * dn;
        float2 v0 = __half22float2(hp[(size_t)s0 * 64 + lane]);
        float2 v1 = __half22float2(hp[(size_t)s1 * 64 + lane]);
        float2 v2 = __half22float2(hp[(size_t)s2 * 64 + lane]);
        float2 v3 = __half22float2(hp[(size_t)s3 * 64 + lane]);
        ax = fmaf(v0.x, w0, ax); ay = fmaf(v0.y, w0, ay);
        ax = fmaf(v1.x, w1, ax); ay = fmaf(v1.y, w1, ay);
        ax = fmaf(v2.x, w2, ax); ay = fmaf(v2.y, w2, ay);
        ax = fmaf(v3.x, w3, ax); ay = fmaf(v3.y, w3, ay);
    }
    for (; j < cc; ++j) {
        unsigned int p = (unsigned int)__shfl((int)m, j);
        int s = p & 0x1FFFF; float w = rsqrtf((float)(p >> 17)) * dn;
        float2 v = __half22float2(hp[(size_t)s * 64 + lane]);
        ax = fmaf(v.x, w, ax); ay = fmaf(v.y, w, ay);
    }
    for (int e = o + 64; e < o + c; ++e) {   // rare degree>64 tail
        unsigned int p = emeta[e];
        int s = p & 0x1FFFF; float w = rsqrtf((float)(p >> 17)) * dn;
        float2 v = __half22float2(hp[(size_t)s * 64 + lane]);
        ax = fmaf(v.x, w, ax); ay = fmaf(v.y, w, ay);
    }

    float2 b = ((const float2*)bias)[lane];
    ax += b.x;
    ay += b.y;
    if (do_relu) { ax = fmaxf(ax, 0.f); ay = fmaxf(ay, 0.f); }
    float2 o2; o2.x = ax; o2.y = ay;
    ((float2*)out)[(size_t)node * 64 + lane] = o2;
}

// ---------------- launch ----------------

extern "C" void kernel_launch(void* const* d_in, const int* in_sizes, int n_in,
                              void* d_out, int out_size, void* d_ws, size_t ws_size,
                              hipStream_t stream) {
    const float* x  = (const float*)d_in[0];
    const int* edge = (const int*)d_in[2];
    const float* W1 = (const float*)d_in[5];
    const float* b1 = (const float*)d_in[6];
    const float* W2 = (const float*)d_in[7];
    const float* b2 = (const float*)d_in[8];

    int n = in_sizes[0] / NCH;
    int E = in_sizes[2] / 2;
    const int* srcp = edge;       // edge_index[0]
    const int* dstp = edge + E;   // edge_index[1]

    char* ws = (char*)d_ws;
    int*   counts  = (int*)ws;   ws += (size_t)n * 4;
    int*   incl    = (int*)ws;   ws += (size_t)n * 4;
    int*   offsets = (int*)ws;   ws += (size_t)n * 4;
    int*   cursor  = (int*)ws;   ws += (size_t)n * 4;
    int*   bsums   = (int*)ws;   ws += 1024;
    uintptr_t pw = ((uintptr_t)ws + 255) & ~(uintptr_t)255;
    __half* Wt1 = (__half*)pw;   pw += 2048 * 16;
    __half* Wt2 = (__half*)pw;   pw += 2048 * 16;
    unsigned int* emeta = (unsigned int*)pw; pw += (size_t)E * 4;
    uintptr_t p = (pw + 255) & ~(uintptr_t)255;
    __half* h = (__half*)p;      // n*128 fp16 = 25.6 MB
    float* out = (float*)d_out;

    hipMemsetAsync(counts, 0, (size_t)n * 4, stream);

    wprep_kernel<<<16, 256, 0, stream>>>(W1, W2, Wt1, Wt2);
    count_kernel<<<(E + 255) / 256, 256, 0, stream>>>(dstp, counts, E);

    int nb = (n + 1023) / 1024;   // 98 <= 128
    scan1_kernel<<<nb, 1024, 0, stream>>>(counts, incl, bsums, n);
    scan2_kernel<<<1, 128, 0, stream>>>(bsums, nb);
    offsets_kernel<<<(n + 255) / 256, 256, 0, stream>>>(incl, counts, bsums, offsets, cursor, n);
    // 512 blocks = 64 blocks per dst-range group; group = blockIdx & 7 -> XCD
    fill_kernel<<<512, 256, 0, stream>>>(srcp, dstp, counts, cursor, emeta, E, n);

    int gemm_blocks = (n + 127) / 128;
    int agg_blocks  = (n + 3) / 4;   // 4 waves of 64 per block, 1 node per wave

    // layer 1: h = fp16(x @ W1) ; out = relu(agg(h) + b1)
    gemm_kernel<<<gemm_blocks, 256, 0, stream>>>(x, Wt1, h, n);
    agg_kernel<<<agg_blocks, 256, 0, stream>>>((const __half2*)h, offsets, counts, emeta, b1, out, n, 1);
    // layer 2: h = fp16(out @ W2) ; out = agg(h) + b2
    gemm_kernel<<<gemm_blocks, 256, 0, stream>>>(out, Wt2, h, n);
    agg_kernel<<<agg_blocks, 256, 0, stream>>>((const __half2*)h, offsets, counts, emeta, b2, out, n, 0);
}

// Round 2
// 487.552 us; speedup vs baseline: 1.1290x; 1.1290x over previous
//
#include <hip/hip_runtime.h>
#include <hip/hip_fp16.h>
#include <stdint.h>

#define NCH 128

using half8  = __attribute__((ext_vector_type(8))) _Float16;
using floatx4 = __attribute__((ext_vector_type(4))) float;

// ---------------- CSR construction ----------------

// fused: blocks 0..15 pre-swizzle W1/W2 to fragment order; rest do degree count.
__global__ __launch_bounds__(256) void count_wprep_kernel(const int* __restrict__ dst,
                                                          int* __restrict__ counts, int E,
                                                          const float* __restrict__ W1,
                                                          const float* __restrict__ W2,
                                                          __half* __restrict__ Wt1,
                                                          __half* __restrict__ Wt2) {
    int b = blockIdx.x;
    if (b < 16) {
        // W pre-swizzle: W[128][128] fp32 -> B-fragment-order fp16.
        // Fragment cell c (0..2047): pair p=c>>6 (kc=p>>3, ct=p&7), lane=c&63.
        // Cell holds 8 fp16: B[k][n], n=ct*16+(lane&15), k=kc*32+(lane>>4)*8+j.
        const float* W = (b < 8) ? W1 : W2;
        __half* Wt     = (b < 8) ? Wt1 : Wt2;
        int c = (b & 7) * 256 + threadIdx.x;
        int p = c >> 6, lane = c & 63;
        int kc = p >> 3, ct = p & 7;
        int nn = ct * 16 + (lane & 15);
        int kbase = kc * 32 + (lane >> 4) * 8;
        half8 hv;
#pragma unroll
        for (int j = 0; j < 8; ++j)
            hv[j] = (_Float16)W[(size_t)(kbase + j) * NCH + nn];
        *(half8*)(Wt + (size_t)c * 8) = hv;
    } else {
        int i = (b - 16) * 256 + threadIdx.x;
        if (i < E) atomicAdd(&counts[dst[i]], 1);
    }
}

__global__ __launch_bounds__(1024) void scan1_kernel(const int* __restrict__ counts,
                                                     int* __restrict__ incl,
                                                     int* __restrict__ bsums, int n) {
    __shared__ int tmp[1024];
    int i = blockIdx.x * 1024 + threadIdx.x;
    int v = (i < n) ? counts[i] : 0;
    tmp[threadIdx.x] = v;
    __syncthreads();
    for (int off = 1; off < 1024; off <<= 1) {
        int t = (threadIdx.x >= off) ? tmp[threadIdx.x - off] : 0;
        __syncthreads();
        tmp[threadIdx.x] += t;
        __syncthreads();
    }
    if (i < n) incl[i] = tmp[threadIdx.x];
    if (threadIdx.x == 1023) bsums[blockIdx.x] = tmp[1023];
}

__global__ __launch_bounds__(128) void scan2_kernel(int* __restrict__ bsums, int nb) {
    __shared__ int tmp[128];
    int v = (threadIdx.x < nb) ? bsums[threadIdx.x] : 0;
    tmp[threadIdx.x] = v;
    __syncthreads();
    for (int off = 1; off < 128; off <<= 1) {
        int t = (threadIdx.x >= off) ? tmp[threadIdx.x - off] : 0;
        __syncthreads();
        tmp[threadIdx.x] += t;
        __syncthreads();
    }
    if (threadIdx.x < nb) bsums[threadIdx.x] = tmp[threadIdx.x] - v;  // exclusive
}

__global__ __launch_bounds__(256) void offsets_kernel(const int* __restrict__ incl,
                                                      const int* __restrict__ counts,
                                                      const int* __restrict__ bsums,
                                                      int* __restrict__ offsets,
                                                      int* __restrict__ cursor, int n) {
    int i = blockIdx.x * blockDim.x + threadIdx.x;
    if (i < n) {
        int e = incl[i] - counts[i] + bsums[i >> 10];
        offsets[i] = e;
        cursor[i] = e;
    }
}

// ---------------- fused fill + GEMM1 ----------------
// fill: random 4B scatter of packed meta (src | (deg+1)<<17) — measured at the
// random-write floor (~1.4 TB/s effective, VALUBusy<1%). gemm1 (x@W1 -> h fp16)
// is independent of the CSR chain, so its blocks ride in the same dispatch and
// hide under fill's latency-bound tail.
// gemm: 256 thr = 4 waves; wave does 32 rows x 128 cols via 16x16x32 f16 MFMA.
// Wt fragments (32KB) staged to LDS; epilogue reuses LDS for coalesced stores.
// Layouts (m89/m120-verified): A[m=lane&15][k=(lane>>4)*8+j],
// B[k=(lane>>4)*8+j][n=lane&15], D col=lane&15 row=(lane>>4)*4+reg.

__global__ __launch_bounds__(256) void fill_gemm_kernel(const float* __restrict__ A,
                                                        const __half* __restrict__ Wt,
                                                        __half* __restrict__ C, int n,
                                                        int gemm_blocks,
                                                        const int* __restrict__ src,
                                                        const int* __restrict__ dst,
                                                        const int* __restrict__ counts,
                                                        int* __restrict__ cursor,
                                                        unsigned int* __restrict__ emeta,
                                                        int E) {
    __shared__ float4 lds[2048];   // 32 KB (gemm blocks only; fill path ignores)
    int bid = blockIdx.x;
    if (bid >= gemm_blocks) {
        // ---- fill path ----
        int i = (bid - gemm_blocks) * 256 + threadIdx.x;
        if (i < E) {
            int s = src[i];
            int d = dst[i];
            unsigned int degp1 = (unsigned int)counts[s] + 1u;
            int pos = atomicAdd(&cursor[d], 1);
            emeta[pos] = (unsigned int)s | (degp1 << 17);
        }
        return;
    }
    // ---- gemm path ----
    int t = threadIdx.x;
    for (int i = t; i < 2048; i += 256) lds[i] = ((const float4*)Wt)[i];
    __syncthreads();

    int wave = t >> 6, lane = t & 63;
    int q = lane >> 4, m16 = lane & 15;
    int rowbase = bid * 128 + wave * 32;

    floatx4 acc[2][8];
#pragma unroll
    for (int g = 0; g < 2; ++g)
#pragma unroll
        for (int ct = 0; ct < 8; ++ct) {
            acc[g][ct][0] = 0.f; acc[g][ct][1] = 0.f;
            acc[g][ct][2] = 0.f; acc[g][ct][3] = 0.f;
        }

    const half8* bfr = (const half8*)lds;

    int ra0 = min(rowbase + m16, n - 1);
    int ra1 = min(rowbase + 16 + m16, n - 1);
    const float* pa0 = A + (size_t)ra0 * NCH;
    const float* pa1 = A + (size_t)ra1 * NCH;

#pragma unroll
    for (int kc = 0; kc < 4; ++kc) {
        int ko = kc * 32 + q * 8;
        float4 f0 = *(const float4*)(pa0 + ko);
        float4 f1 = *(const float4*)(pa0 + ko + 4);
        float4 g0 = *(const float4*)(pa1 + ko);
        float4 g1 = *(const float4*)(pa1 + ko + 4);
        half8 a0, a1;
        a0[0] = (_Float16)f0.x; a0[1] = (_Float16)f0.y;
        a0[2] = (_Float16)f0.z; a0[3] = (_Float16)f0.w;
        a0[4] = (_Float16)f1.x; a0[5] = (_Float16)f1.y;
        a0[6] = (_Float16)f1.z; a0[7] = (_Float16)f1.w;
        a1[0] = (_Float16)g0.x; a1[1] = (_Float16)g0.y;
        a1[2] = (_Float16)g0.z; a1[3] = (_Float16)g0.w;
        a1[4] = (_Float16)g1.x; a1[5] = (_Float16)g1.y;
        a1[6] = (_Float16)g1.z; a1[7] = (_Float16)g1.w;
#pragma unroll
        for (int ct = 0; ct < 8; ++ct) {
            half8 b = bfr[(kc * 8 + ct) * 64 + lane];
            acc[0][ct] = __builtin_amdgcn_mfma_f32_16x16x32_f16(a0, b, acc[0][ct], 0, 0, 0);
            acc[1][ct] = __builtin_amdgcn_mfma_f32_16x16x32_f16(a1, b, acc[1][ct], 0, 0, 0);
        }
    }

    __syncthreads();   // all waves done with Wt fragments; reuse LDS as scratch
    float* scr = (float*)lds + wave * 2048;   // 16 rows x 128 f32 per wave
#pragma unroll
    for (int g = 0; g < 2; ++g) {
#pragma unroll
        for (int reg = 0; reg < 4; ++reg)
#pragma unroll
            for (int ct = 0; ct < 8; ++ct)
                scr[(q * 4 + reg) * NCH + ct * 16 + m16] = acc[g][ct][reg];
        // within-wave LDS RAW: compiler inserts lgkmcnt wait; no barrier needed
        int row0 = rowbase + g * 16;
#pragma unroll
        for (int r = 0; r < 16; ++r) {
            int row = row0 + r;
            if (row < n) {
                float2 v = *(float2*)(scr + r * NCH + lane * 2);
                __half2 hh = __floats2half2_rn(v.x, v.y);
                *(unsigned int*)(C + (size_t)row * NCH + lane * 2) = *(unsigned int*)&hh;
            }
        }
    }
}

// ---------------- GEMM with fp16 A (layer 2) ----------------

__global__ __launch_bounds__(256) void gemm_h_kernel(const __half* __restrict__ A,
                                                     const __half* __restrict__ Wt,
                                                     __half* __restrict__ C, int n) {
    __shared__ float4 lds[2048];   // 32 KB
    int t = threadIdx.x;
    for (int i = t; i < 2048; i += 256) lds[i] = ((const float4*)Wt)[i];
    __syncthreads();

    int wave = t >> 6, lane = t & 63;
    int q = lane >> 4, m16 = lane & 15;
    int rowbase = blockIdx.x * 128 + wave * 32;

    floatx4 acc[2][8];
#pragma unroll
    for (int g = 0; g < 2; ++g)
#pragma unroll
        for (int ct = 0; ct < 8; ++ct) {
            acc[g][ct][0] = 0.f; acc[g][ct][1] = 0.f;
            acc[g][ct][2] = 0.f; acc[g][ct][3] = 0.f;
        }

    const half8* bfr = (const half8*)lds;

    int ra0 = min(rowbase + m16, n - 1);
    int ra1 = min(rowbase + 16 + m16, n - 1);
    const _Float16* pa0 = (const _Float16*)A + (size_t)ra0 * NCH;
    const _Float16* pa1 = (const _Float16*)A + (size_t)ra1 * NCH;

#pragma unroll
    for (int kc = 0; kc < 4; ++kc) {
        int ko = kc * 32 + q * 8;
        half8 a0 = *(const half8*)(pa0 + ko);
        half8 a1 = *(const half8*)(pa1 + ko);
#pragma unroll
        for (int ct = 0; ct < 8; ++ct) {
            half8 b = bfr[(kc * 8 + ct) * 64 + lane];
            acc[0][ct] = __builtin_amdgcn_mfma_f32_16x16x32_f16(a0, b, acc[0][ct], 0, 0, 0);
            acc[1][ct] = __builtin_amdgcn_mfma_f32_16x16x32_f16(a1, b, acc[1][ct], 0, 0, 0);
        }
    }

    __syncthreads();
    float* scr = (float*)lds + wave * 2048;
#pragma unroll
    for (int g = 0; g < 2; ++g) {
#pragma unroll
        for (int reg = 0; reg < 4; ++reg)
#pragma unroll
            for (int ct = 0; ct < 8; ++ct)
                scr[(q * 4 + reg) * NCH + ct * 16 + m16] = acc[g][ct][reg];
        int row0 = rowbase + g * 16;
#pragma unroll
        for (int r = 0; r < 16; ++r) {
            int row = row0 + r;
            if (row < n) {
                float2 v = *(float2*)(scr + r * NCH + lane * 2);
                __half2 hh = __floats2half2_rn(v.x, v.y);
                *(unsigned int*)(C + (size_t)row * NCH + lane * 2) = *(unsigned int*)&hh;
            }
        }
    }
}

// ---------------- Aggregation ----------------
// One wave per node; h fp16 (256B rows). 4B metas preloaded (coalesced) and
// broadcast via shfl; 4 independent row gathers in flight.
// out_fp16: store __half2 (layer-1 activations feed gemm2 which casts to fp16
// anyway — numerically equivalent, halves store+reload traffic).

__global__ __launch_bounds__(256) void agg_kernel(const __half2* __restrict__ hp,
                                                  const int* __restrict__ offsets,
                                                  const int* __restrict__ counts,
                                                  const unsigned int* __restrict__ emeta,
                                                  const float* __restrict__ bias,
                                                  void* __restrict__ outp,
                                                  int n, int do_relu, int out_fp16) {
    int gw = (blockIdx.x * blockDim.x + threadIdx.x) >> 6;
    int lane = threadIdx.x & 63;
    if (gw >= n) return;
    int node = gw;

    int o = offsets[node];
    int c = counts[node];
    float dn = rsqrtf((float)(c + 1));

    float2 hv = __half22float2(hp[(size_t)node * 64 + lane]);
    float w0s = dn * dn;
    float ax = hv.x * w0s, ay = hv.y * w0s;

    unsigned int m = (lane < c) ? emeta[o + lane] : 0u;
    int cc = min(c, 64);
    int j = 0;
    for (; j + 4 <= cc; j += 4) {
        unsigned int p0 = (unsigned int)__shfl((int)m, j);
        unsigned int p1 = (unsigned int)__shfl((int)m, j + 1);
        unsigned int p2 = (unsigned int)__shfl((int)m, j + 2);
        unsigned int p3 = (unsigned int)__shfl((int)m, j + 3);
        int s0 = p0 & 0x1FFFF; float w0 = rsqrtf((float)(p0 >> 17)) * dn;
        int s1 = p1 & 0x1FFFF; float w1 = rsqrtf((float)(p1 >> 17)) * dn;
        int s2 = p2 & 0x1FFFF; float w2 = rsqrtf((float)(p2 >> 17)) * dn;
        int s3 = p3 & 0x1FFFF; float w3 = rsqrtf((float)(p3 >> 17)) * dn;
        float2 v0 = __half22float2(hp[(size_t)s0 * 64 + lane]);
        float2 v1 = __half22float2(hp[(size_t)s1 * 64 + lane]);
        float2 v2 = __half22float2(hp[(size_t)s2 * 64 + lane]);
        float2 v3 = __half22float2(hp[(size_t)s3 * 64 + lane]);
        ax = fmaf(v0.x, w0, ax); ay = fmaf(v0.y, w0, ay);
        ax = fmaf(v1.x, w1, ax); ay = fmaf(v1.y, w1, ay);
        ax = fmaf(v2.x, w2, ax); ay = fmaf(v2.y, w2, ay);
        ax = fmaf(v3.x, w3, ax); ay = fmaf(v3.y, w3, ay);
    }
    for (; j < cc; ++j) {
        unsigned int p = (unsigned int)__shfl((int)m, j);
        int s = p & 0x1FFFF; float w = rsqrtf((float)(p >> 17)) * dn;
        float2 v = __half22float2(hp[(size_t)s * 64 + lane]);
        ax = fmaf(v.x, w, ax); ay = fmaf(v.y, w, ay);
    }
    for (int e = o + 64; e < o + c; ++e) {   // rare degree>64 tail
        unsigned int p = emeta[e];
        int s = p & 0x1FFFF; float w = rsqrtf((float)(p >> 17)) * dn;
        float2 v = __half22float2(hp[(size_t)s * 64 + lane]);
        ax = fmaf(v.x, w, ax); ay = fmaf(v.y, w, ay);
    }

    float2 b = ((const float2*)bias)[lane];
    ax += b.x;
    ay += b.y;
    if (do_relu) { ax = fmaxf(ax, 0.f); ay = fmaxf(ay, 0.f); }
    if (out_fp16) {
        __half2 hh = __floats2half2_rn(ax, ay);
        ((__half2*)outp)[(size_t)node * 64 + lane] = hh;
    } else {
        float2 o2; o2.x = ax; o2.y = ay;
        ((float2*)outp)[(size_t)node * 64 + lane] = o2;
    }
}

// ---------------- launch ----------------

extern "C" void kernel_launch(void* const* d_in, const int* in_sizes, int n_in,
                              void* d_out, int out_size, void* d_ws, size_t ws_size,
                              hipStream_t stream) {
    const float* x  = (const float*)d_in[0];
    const int* edge = (const int*)d_in[2];
    const float* W1 = (const float*)d_in[5];
    const float* b1 = (const float*)d_in[6];
    const float* W2 = (const float*)d_in[7];
    const float* b2 = (const float*)d_in[8];

    int n = in_sizes[0] / NCH;
    int E = in_sizes[2] / 2;
    const int* srcp = edge;       // edge_index[0]
    const int* dstp = edge + E;   // edge_index[1]

    char* ws = (char*)d_ws;
    int*   counts  = (int*)ws;   ws += (size_t)n * 4;
    int*   incl    = (int*)ws;   ws += (size_t)n * 4;
    int*   offsets = (int*)ws;   ws += (size_t)n * 4;
    int*   cursor  = (int*)ws;   ws += (size_t)n * 4;
    int*   bsums   = (int*)ws;   ws += 1024;
    uintptr_t pw = ((uintptr_t)ws + 255) & ~(uintptr_t)255;
    __half* Wt1 = (__half*)pw;   pw += 2048 * 16;
    __half* Wt2 = (__half*)pw;   pw += 2048 * 16;
    unsigned int* emeta = (unsigned int*)pw; pw += (size_t)E * 4;
    uintptr_t p = (pw + 255) & ~(uintptr_t)255;
    __half* h = (__half*)p;      // n*128 fp16 = 25.6 MB
    float* out = (float*)d_out;
    __half* a1 = (__half*)d_out; // layer-1 fp16 activations alias d_out scratch
                                 // (n*128*2 = 25.6 MB <= out_size 51.2 MB;
                                 //  consumed by gemm2 before agg2 overwrites)

    hipMemsetAsync(counts, 0, (size_t)n * 4, stream);

    int count_blocks = (E + 255) / 256;
    count_wprep_kernel<<<16 + count_blocks, 256, 0, stream>>>(dstp, counts, E, W1, W2, Wt1, Wt2);

    int nb = (n + 1023) / 1024;   // 98 <= 128
    scan1_kernel<<<nb, 1024, 0, stream>>>(counts, incl, bsums, n);
    scan2_kernel<<<1, 128, 0, stream>>>(bsums, nb);
    offsets_kernel<<<(n + 255) / 256, 256, 0, stream>>>(incl, counts, bsums, offsets, cursor, n);

    int gemm_blocks = (n + 127) / 128;
    int fill_blocks = (E + 255) / 256;
    int agg_blocks  = (n + 3) / 4;   // 4 waves of 64 per block, 1 node per wave

    // fused: gemm1 (x@W1 -> h fp16) rides in fill's dispatch — independent work
    // hidden under the latency-bound random scatter.
    fill_gemm_kernel<<<gemm_blocks + fill_blocks, 256, 0, stream>>>(
        x, Wt1, h, n, gemm_blocks, srcp, dstp, counts, cursor, emeta, E);

    // layer 1 aggregate: a1 = fp16(relu(agg(h) + b1))
    agg_kernel<<<agg_blocks, 256, 0, stream>>>((const __half2*)h, offsets, counts, emeta, b1, a1, n, 1, 1);
    // layer 2: h = a1 @ W2 (fp16 A); out = agg(h) + b2 (fp32)
    gemm_h_kernel<<<gemm_blocks, 256, 0, stream>>>(a1, Wt2, h, n);
    agg_kernel<<<agg_blocks, 256, 0, stream>>>((const __half2*)h, offsets, counts, emeta, b2, out, n, 0, 0);
}